// Round 14
// baseline (313.885 us; speedup 1.0000x reference)
//
#include <hip/hip_runtime.h>
#include <hip/hip_bf16.h>
#include <math.h>

// B=4, N=2048, D=512, H=8, HD=64. Inputs/outputs FP32; internals bf16-MFMA.
// Fusions: (1) h = cat@[Wtop;Wcomb], Wcomb = out_w@Wbot precomputed -> no proj GEMM;
// (2) RoPE folded into QKV epilogue via precomputed bf16 (cos,sin) table.
// R10: prefetch distance, not LDS, is what absorbs global latency.
// R8: no blind __launch_bounds__ 2nd arg. R13: ffn BK=64 won (kept).
// R14: attn v9 — barrier-free K-loop. K frags direct-from-global with one-tile
// prefetch; V in per-wave PRIVATE LDS (in-order same-wave DS => no barriers).
typedef __bf16 bf16;
typedef __bf16 bf16x2 __attribute__((ext_vector_type(2)));
typedef __bf16 bf16x4 __attribute__((ext_vector_type(4)));
typedef __bf16 bf16x8 __attribute__((ext_vector_type(8)));
typedef float f32x4 __attribute__((ext_vector_type(4)));
typedef float f32x16 __attribute__((ext_vector_type(16)));

#define MFMA16(a, b, c) __builtin_amdgcn_mfma_f32_16x16x32_bf16(a, b, c, 0, 0, 0)
#define MFMA32(a, b, c) __builtin_amdgcn_mfma_f32_32x32x16_bf16(a, b, c, 0, 0, 0)

// MFMA fragment facts (guide-verified on gfx950):
//  16x16x32: A: lane holds A[m=lane&15][k=(lane>>4)*8+j]; C/D: reg r -> D[(lane>>4)*4+r][lane&15]
//  32x32x16: A: lane holds A[m=lane&31][k=(lane>>5)*8+j]; B: B[k=(lane>>5)*8+j][n=lane&31]
//            C/D: reg r -> D[row=(r&3)+8*(r>>2)+4*(lane>>5)][col=lane&31]

// ------------- prep: transposes/casts + x-cast + bias-fuse + rope table -----
__global__ __launch_bounds__(256) void prep_kernel(
    const float* __restrict__ wqkv_w, const float* __restrict__ out_w,
    const float* __restrict__ ffn1_w, const float* __restrict__ ffn2_w,
    const float* __restrict__ x, const float* __restrict__ freqs,
    const float* __restrict__ ffn1_b, const float* __restrict__ out_b,
    bf16* __restrict__ wqkv_t, bf16* __restrict__ ffn2_t,
    bf16* __restrict__ fused_t, bf16* __restrict__ ffn1bt,
    bf16* __restrict__ out_cast, bf16* __restrict__ cat,
    float* __restrict__ bias_f, unsigned* __restrict__ tab)
{
    const int bid = blockIdx.x, tid = threadIdx.x;
    __shared__ bf16 tile[32][33];
    __shared__ float red[256];
    if (bid >= 6672) {                 // rope table: 256 blocks, packed bf16 (cos,sin)
        int i = (bid - 6672) * 1024 + tid * 4;
        const float4 f = *(const float4*)(&freqs[i]);
        float s0, c0, s1, c1, s2, c2, s3, c3;
        __sincosf(f.x, &s0, &c0); __sincosf(f.y, &s1, &c1);
        __sincosf(f.z, &s2, &c2); __sincosf(f.w, &s3, &c3);
        union { bf16x2 h2; unsigned u; } p0, p1, p2, p3;
        p0.h2[0] = (bf16)c0; p0.h2[1] = (bf16)s0;
        p1.h2[0] = (bf16)c1; p1.h2[1] = (bf16)s1;
        p2.h2[0] = (bf16)c2; p2.h2[1] = (bf16)s2;
        p3.h2[0] = (bf16)c3; p3.h2[1] = (bf16)s3;
        uint4 o = {p0.u, p1.u, p2.u, p3.u};
        *(uint4*)(&tab[i]) = o;
        return;
    }
    if (bid >= 6656) {                 // bias_f[n] = ffn1_b[n] + sum_i out_b[i]*Wbot[i][n]
        const int n = (bid - 6656) * 64 + (tid & 63);
        const int ic = tid >> 6;
        float acc = 0.f;
#pragma unroll 8
        for (int i = ic * 128; i < ic * 128 + 128; i++)
            acc += out_b[i] * ffn1_w[(size_t)(512 + i) * 1024 + n];
        red[tid] = acc;
        __syncthreads();
        if (tid < 64)
            bias_f[n] = ffn1_b[n] + red[tid] + red[tid + 64] + red[tid + 128] + red[tid + 192];
        return;
    }
    if (bid >= 2560) {                 // cast_x: 4096 blocks
        int i = (bid - 2560) * 256 + tid;
        int row = i >> 7, col = (i & 127) << 2;
        const float4 v = *(const float4*)(&x[(size_t)row * 512 + col]);
        bf16x4 o; o[0] = (bf16)v.x; o[1] = (bf16)v.y; o[2] = (bf16)v.z; o[3] = (bf16)v.w;
        *(bf16x4*)(&cat[(size_t)row * 1024 + col]) = o;
        return;
    }
    if (bid >= 2304) {                 // out_w cast: 256 blocks (512x512)
        int i = (bid - 2304) * 1024 + tid * 4;
        const float4 v = *(const float4*)(&out_w[i]);
        bf16x4 o; o[0] = (bf16)v.x; o[1] = (bf16)v.y; o[2] = (bf16)v.z; o[3] = (bf16)v.w;
        *(bf16x4*)(&out_cast[i]) = o;
        return;
    }
    // transposes: src (RxC) f32 -> dst (CxR region) bf16 with dst stride ldd
    const float* src; bf16* dst; int C, ldd, bx, by;
    if (bid < 768)       { src = wqkv_w;            dst = wqkv_t;  C = 1536; ldd = 512;  int r = bid;        bx = r % 48; by = r / 48; }
    else if (bid < 1280) { src = ffn2_w;            dst = ffn2_t;  C = 512;  ldd = 1024; int r = bid - 768;  bx = r % 16; by = r / 16; }
    else if (bid < 1792) { src = ffn1_w;            dst = fused_t; C = 1024; ldd = 1024; int r = bid - 1280; bx = r % 32; by = r / 32; }
    else                 { src = ffn1_w + 512*1024; dst = ffn1bt;  C = 1024; ldd = 512;  int r = bid - 1792; bx = r % 32; by = r / 32; }
    const int tx = tid & 31, ty = tid >> 5;
    const int xx = bx * 32 + tx;
#pragma unroll
    for (int j = 0; j < 4; j++)
        tile[ty + 8 * j][tx] = (bf16)src[(size_t)(by * 32 + ty + 8 * j) * C + xx];
    __syncthreads();
    const int x2 = by * 32 + tx;
#pragma unroll
    for (int j = 0; j < 4; j++)
        dst[(size_t)(bx * 32 + ty + 8 * j) * ldd + x2] = tile[tx][ty + 8 * j];
}

// ---------------- QKV GEMM (+fused RoPE epilogue) + Wcomb GEMM, ONE launch --
__global__ __launch_bounds__(256) void qkv_wcomb_kernel(
    const bf16* __restrict__ cat, const bf16* __restrict__ wqkv_t,
    const float* __restrict__ wqkv_b, const unsigned* __restrict__ tab,
    bf16* __restrict__ qbuf, bf16* __restrict__ kbuf, bf16* __restrict__ vbuf,
    const bf16* __restrict__ ffn1bt, const bf16* __restrict__ out_cast,
    bf16* __restrict__ fused_t)
{
    const int bid = blockIdx.x;
    const bool isqkv = bid < 768;
    const bf16* A; const bf16* Bt; int lda, m0, n0;
    if (isqkv) { A = cat;    lda = 1024; Bt = wqkv_t;   n0 = (bid % 12) * 128; m0 = (bid / 12) * 128; }
    else       { int r = bid - 768;
                 A = ffn1bt; lda = 512;  Bt = out_cast; n0 = (r & 3) * 128;    m0 = (r >> 2) * 128; }
    const int K = 512;

    const int tid = threadIdx.x;
    const int lane = tid & 63, wave = tid >> 6;
    const int wm = wave >> 1, wn = wave & 1;
    const int l15 = lane & 15, quad = lane >> 4;

    __shared__ __align__(16) char smem[16384];
    bf16* As = (bf16*)smem;            // 128x32
    bf16* Bs = (bf16*)(smem + 8192);   // 128x32
    unsigned* tabs = (unsigned*)smem;  // overlay post-loop: 128 rows x 32 pairs

    const int c0 = tid, c1 = tid + 256;
    const int r0 = c0 >> 2, kc0 = (c0 & 3) << 3;
    const int r1 = c1 >> 2, kc1 = (c1 & 3) << 3;
    const bf16* pA0 = &A[(size_t)(m0 + r0) * lda + kc0];
    const bf16* pA1 = &A[(size_t)(m0 + r1) * lda + kc1];
    const bf16* pB0 = &Bt[(size_t)(n0 + r0) * K + kc0];
    const bf16* pB1 = &Bt[(size_t)(n0 + r1) * K + kc1];

    const f32x4 zero = {0.f, 0.f, 0.f, 0.f};
    f32x4 acc[4][4];
#pragma unroll
    for (int i = 0; i < 4; i++)
#pragma unroll
        for (int j = 0; j < 4; j++) acc[i][j] = zero;

    bf16x8 ra0 = *(const bf16x8*)pA0;
    bf16x8 ra1 = *(const bf16x8*)pA1;
    bf16x8 rb0 = *(const bf16x8*)pB0;
    bf16x8 rb1 = *(const bf16x8*)pB1;

    for (int k0 = 0; k0 < K; k0 += 32) {
        __syncthreads();
        *(bf16x8*)(&As[c0 * 8]) = ra0;
        *(bf16x8*)(&As[c1 * 8]) = ra1;
        *(bf16x8*)(&Bs[c0 * 8]) = rb0;
        *(bf16x8*)(&Bs[c1 * 8]) = rb1;
        __syncthreads();
        if (k0 + 32 < K) {
            ra0 = *(const bf16x8*)(pA0 + k0 + 32);
            ra1 = *(const bf16x8*)(pA1 + k0 + 32);
            rb0 = *(const bf16x8*)(pB0 + k0 + 32);
            rb1 = *(const bf16x8*)(pB1 + k0 + 32);
        }
        bf16x8 af[4], bfv[4];
#pragma unroll
        for (int t = 0; t < 4; t++) {
            af[t]  = *(const bf16x8*)(&As[(wm * 64 + t * 16 + l15) * 32 + quad * 8]);
            bfv[t] = *(const bf16x8*)(&Bs[(wn * 64 + t * 16 + l15) * 32 + quad * 8]);
        }
#pragma unroll
        for (int mt = 0; mt < 4; mt++)
#pragma unroll
            for (int nt = 0; nt < 4; nt++)
                acc[mt][nt] = MFMA16(af[mt], bfv[nt], acc[mt][nt]);
    }

    const int row_base = m0 + wm * 64;
    const int col_base = n0 + wn * 64;

    if (isqkv) {
        const int sector = col_base >> 9;        // 0=q 1=k 2=v, uniform per BLOCK
        const bool dorope = sector < 2;
        if (dorope) {                            // stage this block's rope table
            __syncthreads();                     // K-loop LDS reads done
#pragma unroll
            for (int ps = 0; ps < 4; ps++) {
                int idx = ps * 1024 + tid * 4;
                *(uint4*)(&tabs[idx]) = *(const uint4*)(&tab[(size_t)m0 * 32 + idx]);
            }
            __syncthreads();
        }
        const float SCQ = 0.125f * 1.44269504089f;
        bf16* dstbase = (sector == 0) ? qbuf : (sector == 1 ? kbuf : vbuf);
#pragma unroll
        for (int nt = 0; nt < 4; nt++) {
            const int col = col_base + nt * 16 + l15;
            const int cq = col & 511;
            const int h = cq >> 6, hd = cq & 63;
            const float bv = wqkv_b[col];
            const int ihalf = hd >> 1;
            const bool odd = (hd & 1) != 0;
#pragma unroll
            for (int mt = 0; mt < 4; mt++) {
#pragma unroll
                for (int r = 0; r < 4; r++) {
                    const int mrow = row_base + mt * 16 + quad * 4 + r;   // b*2048+n
                    float v = acc[mt][nt][r] + bv;
                    float o = v;
                    if (dorope) {
                        float p = __shfl_xor(v, 1);      // partner column col^1
                        const int rl = wm * 64 + mt * 16 + quad * 4 + r;  // mrow-m0
                        union { unsigned u; bf16x2 h2; } t2;
                        t2.u = tabs[rl * 32 + ihalf];
                        float cs = t2.h2[0], sn = t2.h2[1];
                        o = odd ? (p * sn + v * cs) : (v * cs - p * sn);
                        if (sector == 0) o *= SCQ;
                    }
                    const int b = mrow >> 11, n = mrow & 2047;
                    dstbase[(((size_t)b * 8 + h) * 2048 + n) * 64 + hd] = (bf16)o;
                }
            }
        }
    } else {
#pragma unroll
        for (int nt = 0; nt < 4; nt++) {
            const int col = col_base + nt * 16 + l15;
#pragma unroll
            for (int mt = 0; mt < 4; mt++) {
#pragma unroll
                for (int r = 0; r < 4; r++) {
                    const int row = row_base + mt * 16 + quad * 4 + r;
                    fused_t[(size_t)row * 1024 + 512 + col] = (bf16)acc[mt][nt][r];
                }
            }
        }
    }
}

// ---------------- 128x128 MFMA GEMM, BK=64, stride-72 LDS, for ffn1 / ffn2 --
template <int MODE>
__global__ __launch_bounds__(256) void gemm_mfma(
    const bf16* __restrict__ A, int lda, const bf16* __restrict__ Bt,
    const float* __restrict__ bias, void* __restrict__ outv,
    const float* __restrict__ auxf, int K)
{
    const int tid = threadIdx.x;
    const int lane = tid & 63, wave = tid >> 6;
    const int wm = wave >> 1, wn = wave & 1;
    const int l15 = lane & 15, quad = lane >> 4;
    const int m0 = blockIdx.y * 128;
    const int n0 = blockIdx.x * 128;

    __shared__ bf16 As[128 * 72];
    __shared__ bf16 Bs[128 * 72];

    int row[4], kc[4];
    const bf16 *pA[4], *pB[4];
#pragma unroll
    for (int i = 0; i < 4; i++) {
        int c = tid + i * 256;
        row[i] = c >> 3; kc[i] = (c & 7) << 3;
        pA[i] = &A[(size_t)(m0 + row[i]) * lda + kc[i]];
        pB[i] = &Bt[(size_t)(n0 + row[i]) * K + kc[i]];
    }

    const f32x4 zero = {0.f, 0.f, 0.f, 0.f};
    f32x4 acc[4][4];
#pragma unroll
    for (int i = 0; i < 4; i++)
#pragma unroll
        for (int j = 0; j < 4; j++) acc[i][j] = zero;

    bf16x8 ra[4], rb[4];
#pragma unroll
    for (int i = 0; i < 4; i++) { ra[i] = *(const bf16x8*)pA[i]; rb[i] = *(const bf16x8*)pB[i]; }

    for (int k0 = 0; k0 < K; k0 += 64) {
        __syncthreads();
#pragma unroll
        for (int i = 0; i < 4; i++) {
            *(bf16x8*)(&As[row[i] * 72 + kc[i]]) = ra[i];
            *(bf16x8*)(&Bs[row[i] * 72 + kc[i]]) = rb[i];
        }
        __syncthreads();
        if (k0 + 64 < K) {
#pragma unroll
            for (int i = 0; i < 4; i++) {
                ra[i] = *(const bf16x8*)(pA[i] + k0 + 64);
                rb[i] = *(const bf16x8*)(pB[i] + k0 + 64);
            }
        }
#pragma unroll
        for (int kk = 0; kk < 2; kk++) {
            bf16x8 af[4], bfv[4];
#pragma unroll
            for (int t = 0; t < 4; t++) {
                af[t]  = *(const bf16x8*)(&As[(wm * 64 + t * 16 + l15) * 72 + kk * 32 + quad * 8]);
                bfv[t] = *(const bf16x8*)(&Bs[(wn * 64 + t * 16 + l15) * 72 + kk * 32 + quad * 8]);
            }
#pragma unroll
            for (int mt = 0; mt < 4; mt++)
#pragma unroll
                for (int nt = 0; nt < 4; nt++)
                    acc[mt][nt] = MFMA16(af[mt], bfv[nt], acc[mt][nt]);
        }
    }

    const int row_base = m0 + wm * 64;
    const int col_base = n0 + wn * 64;
#pragma unroll
    for (int nt = 0; nt < 4; nt++) {
        const int col = col_base + nt * 16 + l15;
        const float bv = bias[col];
#pragma unroll
        for (int mt = 0; mt < 4; mt++) {
#pragma unroll
            for (int r = 0; r < 4; r++) {
                const int row2 = row_base + mt * 16 + quad * 4 + r;
                float v = acc[mt][nt][r] + bv;
                if constexpr (MODE == 2) {
                    ((bf16*)outv)[(size_t)row2 * 1024 + col] = (bf16)v;
                } else {
                    v += auxf[(size_t)row2 * 512 + col];
                    ((float*)outv)[(size_t)row2 * 512 + col] = v;
                }
            }
        }
    }
}

// ---------------- attention v9: barrier-free loop, private-LDS V ------------
// Grid 1024; 512 threads = 8 waves: qg(2) x kh(4 key-quarter). Each wave
// consumes only its own 32-key quarter: K fragments come straight from global
// (prefetched one tile ahead; qg-pair loads are L1/L2 hits), V is staged into
// a per-wave PRIVATE LDS quarter. Same-wave DS ops are in-order, so the
// PV(t-1)-read -> V(t)-write program order makes a single V buffer safe with
// ZERO __syncthreads in the loop. Sync only for the epilogue reduction.
__global__ __launch_bounds__(512) void attn_kernel(const bf16* __restrict__ qb,
                                                   const bf16* __restrict__ kb,
                                                   const bf16* __restrict__ vb,
                                                   bf16* __restrict__ cat)
{
    __shared__ __align__(16) char smem[38912];
    // per-wave V quarter: [64 dims][32 keys], stride 38 elems (19 dwords,
    // gcd(19,32)=1 -> reads conflict-free; writes 2-way). 4864 B per wave.

    const int tid = threadIdx.x, lane = tid & 63, wave = tid >> 6;
    const int l31 = lane & 31, half = lane >> 5;
    const int qg = wave >> 2, kh = wave & 3;
    const int bh = blockIdx.x >> 5, qt = blockIdx.x & 31;
    const int b = bh >> 3, h = bh & 7;
    const size_t base = (size_t)bh * 2048 * 64;
    const int m0 = qt * 64 + qg * 32;
    const int ko = kh * 32;

    bf16* Vq = (bf16*)(smem + wave * 4864);

    bf16x8 aq[4];
#pragma unroll
    for (int k4 = 0; k4 < 4; k4++)
        aq[k4] = *(const bf16x8*)(&qb[base + (size_t)(m0 + l31) * 64 + k4 * 16 + half * 8]);

    f32x16 accO[2];
#pragma unroll
    for (int i = 0; i < 16; i++) { accO[0][i] = 0.f; accO[1][i] = 0.f; }
    float lsum = 0.f;

    // K fragments direct from global: lane reads row ko+l31, dims k4*16+half*8
    const bf16* kf0 = kb + base + (size_t)(ko + l31) * 64 + half * 8;
    // V staging: lane handles local key pair (2*p2, 2*p2+1), dim group dg*16
    const int p2 = lane & 15, dg = lane >> 4;
    const bf16* vf0 = vb + base + (size_t)(ko + 2 * p2) * 64 + dg * 16;

    bf16x8 kfrag[4], v00, v01, v10, v11;
    auto loadK = [&](int key0) {
#pragma unroll
        for (int k4 = 0; k4 < 4; k4++)
            kfrag[k4] = *(const bf16x8*)(kf0 + (size_t)key0 * 64 + k4 * 16);
    };
    auto loadV = [&](int key0) {
        const bf16* p = vf0 + (size_t)key0 * 64;
        v00 = *(const bf16x8*)(p);
        v01 = *(const bf16x8*)(p + 8);
        v10 = *(const bf16x8*)(p + 64);
        v11 = *(const bf16x8*)(p + 72);
    };

    union Bu { bf16x8 v; unsigned u[4]; };
    Bu B0p, B1p;
    auto pv = [&]() {
#pragma unroll
        for (int dh = 0; dh < 2; dh++) {
            bf16x8 av0 = *(const bf16x8*)(&Vq[(dh * 32 + l31) * 38 + half * 8]);
            bf16x8 av1 = *(const bf16x8*)(&Vq[(dh * 32 + l31) * 38 + 16 + half * 8]);
            accO[dh] = MFMA32(av0, B0p.v, accO[dh]);
            accO[dh] = MFMA32(av1, B1p.v, accO[dh]);
        }
    };

    loadK(0); loadV(0);
#pragma unroll
    for (int kt = 0; kt < 16; kt++) {
        // S(t) from register K fragments (loaded a full tile ago)
        f32x16 s;
#pragma unroll
        for (int i = 0; i < 16; i++) s[i] = 0.f;
#pragma unroll
        for (int k4 = 0; k4 < 4; k4++) s = MFMA32(kfrag[k4], aq[k4], s);
        if (kt < 15) loadK((kt + 1) * 128);
        // PV(t-1): reads Vq BEFORE this tile's V-write (in-order DS => safe)
        if (kt > 0) pv();
        // V-write(t): transpose into private quarter
#pragma unroll
        for (int j = 0; j < 8; j++) {
            bf16x2 pr; pr[0] = v00[j]; pr[1] = v10[j];
            *(bf16x2*)(&Vq[(dg * 16 + j) * 38 + 2 * p2]) = pr;
        }
#pragma unroll
        for (int j = 0; j < 8; j++) {
            bf16x2 pr; pr[0] = v01[j]; pr[1] = v11[j];
            *(bf16x2*)(&Vq[(dg * 16 + 8 + j) * 38 + 2 * p2]) = pr;
        }
        if (kt < 15) loadV((kt + 1) * 128);
        // exp/pack(t) -> B0p/B1p (consumed by next iteration's pv)
        float p[16];
#pragma unroll
        for (int r = 0; r < 16; r++) p[r] = __builtin_amdgcn_exp2f(s[r]);
        lsum += (((p[0] + p[1]) + (p[2] + p[3])) + ((p[4] + p[5]) + (p[6] + p[7])))
              + (((p[8] + p[9]) + (p[10] + p[11])) + ((p[12] + p[13]) + (p[14] + p[15])));
        unsigned pk[8];
#pragma unroll
        for (int i2 = 0; i2 < 8; i2++) {
            union { bf16x2 hh; unsigned u; } t;
            t.hh[0] = (bf16)p[2 * i2]; t.hh[1] = (bf16)p[2 * i2 + 1];
            pk[i2] = t.u;
        }
        const unsigned sa = half ? pk[0] : pk[2];
        const unsigned sb = half ? pk[1] : pk[3];
        const unsigned sc2 = half ? pk[4] : pk[6];
        const unsigned sd = half ? pk[5] : pk[7];
        const unsigned ra = (unsigned)__shfl_xor((int)sa, 32);
        const unsigned rb = (unsigned)__shfl_xor((int)sb, 32);
        const unsigned rc = (unsigned)__shfl_xor((int)sc2, 32);
        const unsigned rd = (unsigned)__shfl_xor((int)sd, 32);
        B0p.u[0] = half ? ra : pk[0];
        B0p.u[1] = half ? rb : pk[1];
        B0p.u[2] = half ? pk[2] : ra;
        B0p.u[3] = half ? pk[3] : rb;
        B1p.u[0] = half ? rc : pk[4];
        B1p.u[1] = half ? rd : pk[5];
        B1p.u[2] = half ? pk[6] : rc;
        B1p.u[3] = half ? pk[7] : rd;
    }
    pv();   // drain: PV for tile 15 (Vq holds tile 15's quarter)

    // 4-way kh reduction per qg through LDS (stride-33 f32, conflict-free).
    // Overlay is only touched after the barrier; all waves have finished.
    auto slotp = [&](int s2) { return (float*)smem + ((s2 * 2 + qg) * 64 + lane) * 33; };
    __syncthreads();
    if (kh == 1 || kh == 3) {
        float* pr2 = slotp(kh >> 1);
#pragma unroll
        for (int dh = 0; dh < 2; dh++)
#pragma unroll
            for (int r = 0; r < 16; r++) pr2[dh * 16 + r] = accO[dh][r];
        pr2[32] = lsum;
    }
    __syncthreads();
    if (kh == 0 || kh == 2) {
        float* pr2 = slotp(kh >> 1);
#pragma unroll
        for (int dh = 0; dh < 2; dh++)
#pragma unroll
            for (int r = 0; r < 16; r++) accO[dh][r] += pr2[dh * 16 + r];
        lsum += pr2[32];
    }
    __syncthreads();
    if (kh == 2) {
        float* pr2 = slotp(0);
#pragma unroll
        for (int dh = 0; dh < 2; dh++)
#pragma unroll
            for (int r = 0; r < 16; r++) pr2[dh * 16 + r] = accO[dh][r];
        pr2[32] = lsum;
    }
    __syncthreads();
    if (kh == 0) {
        float* pr2 = slotp(0);
#pragma unroll
        for (int dh = 0; dh < 2; dh++)
#pragma unroll
            for (int r = 0; r < 16; r++) accO[dh][r] += pr2[dh * 16 + r];
        lsum += pr2[32];
        lsum += __shfl_xor(lsum, 32);  // merge key-halves
        const float inv = 1.0f / lsum;
        const int n = m0 + l31;
        bf16* aor = cat + ((size_t)b * 2048 + n) * 1024 + 512 + h * 64;
#pragma unroll
        for (int dh = 0; dh < 2; dh++) {
#pragma unroll
            for (int g = 0; g < 4; g++) {
                bf16x4 o4;
#pragma unroll
                for (int e = 0; e < 4; e++) o4[e] = (bf16)(accO[dh][g * 4 + e] * inv);
                *(bf16x4*)(&aor[dh * 32 + g * 8 + half * 4]) = o4;
            }
        }
    }
}

// ------------- LayerNorm + tanh-GELU, one block per row, in place (bf16) ---
__global__ __launch_bounds__(256) void ln_gelu_kernel(bf16* __restrict__ hb,
                                                      const float* __restrict__ g,
                                                      const float* __restrict__ bt)
{
    const int row = blockIdx.x, tid = threadIdx.x;
    const int lane = tid & 63, wave = tid >> 6;
    bf16* hr = hb + (size_t)row * 1024;
    bf16x4 hv = *(const bf16x4*)(&hr[tid * 4]);
    float v0 = hv[0], v1 = hv[1], v2 = hv[2], v3 = hv[3];
    float s = v0 + v1 + v2 + v3;
    float q = v0 * v0 + v1 * v1 + v2 * v2 + v3 * v3;
    for (int o = 32; o; o >>= 1) { s += __shfl_xor(s, o); q += __shfl_xor(q, o); }
    __shared__ float red[8];
    if (lane == 0) { red[wave] = s; red[4 + wave] = q; }
    __syncthreads();
    s = red[0] + red[1] + red[2] + red[3];
    q = red[4] + red[5] + red[6] + red[7];
    const float mu = s * (1.f / 1024.f);
    const float rstd = rsqrtf(q * (1.f / 1024.f) - mu * mu + 1e-5f);
    const float4 gv = *(const float4*)(&g[tid * 4]);
    const float4 bv = *(const float4*)(&bt[tid * 4]);
    float vv[4] = {v0, v1, v2, v3};
    const float gg[4] = {gv.x, gv.y, gv.z, gv.w};
    const float bb[4] = {bv.x, bv.y, bv.z, bv.w};
    bf16x4 o4;
#pragma unroll
    for (int i = 0; i < 4; i++) {
        float y = (vv[i] - mu) * rstd * gg[i] + bb[i];
        float t = 1.5957691216f * y * (1.0f + 0.044715f * y * y);
        float e = __builtin_amdgcn_exp2f(-1.44269504089f * t);
        o4[i] = (bf16)(y * __builtin_amdgcn_rcpf(1.0f + e));
    }
    *(bf16x4*)(&hr[tid * 4]) = o4;
}

// ---------------------------------------------------------------------------
extern "C" void kernel_launch(void* const* d_in, const int* in_sizes, int n_in,
                              void* d_out, int out_size, void* d_ws, size_t ws_size,
                              hipStream_t stream) {
    (void)in_sizes; (void)n_in; (void)out_size; (void)ws_size;
    const float* x      = (const float*)d_in[0];
    const float* freqs  = (const float*)d_in[1];
    const float* wqkv_w = (const float*)d_in[2];
    const float* wqkv_b = (const float*)d_in[3];
    const float* out_w  = (const float*)d_in[4];
    const float* out_b  = (const float*)d_in[5];
    const float* ffn1_w = (const float*)d_in[6];
    const float* ffn1_b = (const float*)d_in[7];
    const float* ln_g   = (const float*)d_in[8];
    const float* ln_b   = (const float*)d_in[9];
    const float* ffn2_w = (const float*)d_in[10];
    const float* ffn2_b = (const float*)d_in[11];
    float* out = (float*)d_out;
    bf16* ws   = (bf16*)d_ws;

    bf16* wqkv_t   = ws;                              // 1536x512
    bf16* ffn2_t   = wqkv_t + 1536 * 512;             // 512x1024
    bf16* fused_t  = ffn2_t + 512 * 1024;             // 1024x1024 [Wtop^T | Wcomb^T]
    bf16* ffn1bt   = fused_t + 1024 * 1024;           // 1024x512 (Wbot^T)
    bf16* out_cast = ffn1bt + 1024 * 512;             // 512x512
    bf16* cat      = out_cast + 512 * 512;            // 8192x1024
    bf16* qbuf     = cat + (size_t)8192 * 1024;       // (B,H,N,64)
    bf16* kbuf     = qbuf + (size_t)8192 * 512;
    bf16* vbuf     = kbuf + (size_t)8192 * 512;
    float* bias_f  = (float*)(vbuf + (size_t)8192 * 512);   // 1024 f32
    unsigned* tab  = (unsigned*)(bias_f + 1024);      // 4x2048x32 packed bf16 (cos,sin)
    bf16* hbuf     = qbuf;                            // overlays q+k (dead post-attn)

    prep_kernel<<<6928, 256, 0, stream>>>(wqkv_w, out_w, ffn1_w, ffn2_w, x, freqs,
                                          ffn1_b, out_b,
                                          wqkv_t, ffn2_t, fused_t, ffn1bt, out_cast, cat,
                                          bias_f, tab);
    qkv_wcomb_kernel<<<800, 256, 0, stream>>>(cat, wqkv_t, wqkv_b, tab, qbuf, kbuf, vbuf,
                                              ffn1bt, out_cast, fused_t);
    attn_kernel<<<1024, 512, 0, stream>>>(qbuf, kbuf, vbuf, cat);
    gemm_mfma<2><<<dim3(8, 64), 256, 0, stream>>>(cat, 1024, fused_t, bias_f, hbuf, nullptr, 1024);
    ln_gelu_kernel<<<8192, 256, 0, stream>>>(hbuf, ln_g, ln_b);
    gemm_mfma<3><<<dim3(4, 64), 256, 0, stream>>>(hbuf, 1024, ffn2_t, ffn2_b, out, x, 1024);
}

// Round 15
// 244.965 us; speedup vs baseline: 1.2813x; 1.2813x over previous
//
#include <hip/hip_runtime.h>
#include <hip/hip_bf16.h>
#include <math.h>

// B=4, N=2048, D=512, H=8, HD=64. Inputs/outputs FP32; internals bf16-MFMA.
// Fusions: (1) h = cat@[Wtop;Wcomb], Wcomb = out_w@Wbot precomputed -> no proj GEMM;
// (2) RoPE folded into QKV epilogue via precomputed bf16 (cos,sin) table.
// R10+R14 law: hot MFMA operands must be staged cooperatively through LDS with
// register prefetch — per-lane global gathers stall on latency + TA pressure.
// R8: no blind __launch_bounds__ 2nd arg. R13: BK=64 stride-72 GEMMs won.
// R15: qkv_wcomb also BK=64; attention = R13's v8 (best measured, 63.4 us).
typedef __bf16 bf16;
typedef __bf16 bf16x2 __attribute__((ext_vector_type(2)));
typedef __bf16 bf16x4 __attribute__((ext_vector_type(4)));
typedef __bf16 bf16x8 __attribute__((ext_vector_type(8)));
typedef float f32x4 __attribute__((ext_vector_type(4)));
typedef float f32x16 __attribute__((ext_vector_type(16)));

#define MFMA16(a, b, c) __builtin_amdgcn_mfma_f32_16x16x32_bf16(a, b, c, 0, 0, 0)
#define MFMA32(a, b, c) __builtin_amdgcn_mfma_f32_32x32x16_bf16(a, b, c, 0, 0, 0)

// MFMA fragment facts (guide-verified on gfx950):
//  16x16x32: A: lane holds A[m=lane&15][k=(lane>>4)*8+j]; C/D: reg r -> D[(lane>>4)*4+r][lane&15]
//  32x32x16: A: lane holds A[m=lane&31][k=(lane>>5)*8+j]; B: B[k=(lane>>5)*8+j][n=lane&31]
//            C/D: reg r -> D[row=(r&3)+8*(r>>2)+4*(lane>>5)][col=lane&31]

// ------------- prep: transposes/casts + x-cast + bias-fuse + rope table -----
__global__ __launch_bounds__(256) void prep_kernel(
    const float* __restrict__ wqkv_w, const float* __restrict__ out_w,
    const float* __restrict__ ffn1_w, const float* __restrict__ ffn2_w,
    const float* __restrict__ x, const float* __restrict__ freqs,
    const float* __restrict__ ffn1_b, const float* __restrict__ out_b,
    bf16* __restrict__ wqkv_t, bf16* __restrict__ ffn2_t,
    bf16* __restrict__ fused_t, bf16* __restrict__ ffn1bt,
    bf16* __restrict__ out_cast, bf16* __restrict__ cat,
    float* __restrict__ bias_f, unsigned* __restrict__ tab)
{
    const int bid = blockIdx.x, tid = threadIdx.x;
    __shared__ bf16 tile[32][33];
    __shared__ float red[256];
    if (bid >= 6672) {                 // rope table: 256 blocks, packed bf16 (cos,sin)
        int i = (bid - 6672) * 1024 + tid * 4;
        const float4 f = *(const float4*)(&freqs[i]);
        float s0, c0, s1, c1, s2, c2, s3, c3;
        __sincosf(f.x, &s0, &c0); __sincosf(f.y, &s1, &c1);
        __sincosf(f.z, &s2, &c2); __sincosf(f.w, &s3, &c3);
        union { bf16x2 h2; unsigned u; } p0, p1, p2, p3;
        p0.h2[0] = (bf16)c0; p0.h2[1] = (bf16)s0;
        p1.h2[0] = (bf16)c1; p1.h2[1] = (bf16)s1;
        p2.h2[0] = (bf16)c2; p2.h2[1] = (bf16)s2;
        p3.h2[0] = (bf16)c3; p3.h2[1] = (bf16)s3;
        uint4 o = {p0.u, p1.u, p2.u, p3.u};
        *(uint4*)(&tab[i]) = o;
        return;
    }
    if (bid >= 6656) {                 // bias_f[n] = ffn1_b[n] + sum_i out_b[i]*Wbot[i][n]
        const int n = (bid - 6656) * 64 + (tid & 63);
        const int ic = tid >> 6;
        float acc = 0.f;
#pragma unroll 8
        for (int i = ic * 128; i < ic * 128 + 128; i++)
            acc += out_b[i] * ffn1_w[(size_t)(512 + i) * 1024 + n];
        red[tid] = acc;
        __syncthreads();
        if (tid < 64)
            bias_f[n] = ffn1_b[n] + red[tid] + red[tid + 64] + red[tid + 128] + red[tid + 192];
        return;
    }
    if (bid >= 2560) {                 // cast_x: 4096 blocks
        int i = (bid - 2560) * 256 + tid;
        int row = i >> 7, col = (i & 127) << 2;
        const float4 v = *(const float4*)(&x[(size_t)row * 512 + col]);
        bf16x4 o; o[0] = (bf16)v.x; o[1] = (bf16)v.y; o[2] = (bf16)v.z; o[3] = (bf16)v.w;
        *(bf16x4*)(&cat[(size_t)row * 1024 + col]) = o;
        return;
    }
    if (bid >= 2304) {                 // out_w cast: 256 blocks (512x512)
        int i = (bid - 2304) * 1024 + tid * 4;
        const float4 v = *(const float4*)(&out_w[i]);
        bf16x4 o; o[0] = (bf16)v.x; o[1] = (bf16)v.y; o[2] = (bf16)v.z; o[3] = (bf16)v.w;
        *(bf16x4*)(&out_cast[i]) = o;
        return;
    }
    // transposes: src (RxC) f32 -> dst (CxR region) bf16 with dst stride ldd
    const float* src; bf16* dst; int C, ldd, bx, by;
    if (bid < 768)       { src = wqkv_w;            dst = wqkv_t;  C = 1536; ldd = 512;  int r = bid;        bx = r % 48; by = r / 48; }
    else if (bid < 1280) { src = ffn2_w;            dst = ffn2_t;  C = 512;  ldd = 1024; int r = bid - 768;  bx = r % 16; by = r / 16; }
    else if (bid < 1792) { src = ffn1_w;            dst = fused_t; C = 1024; ldd = 1024; int r = bid - 1280; bx = r % 32; by = r / 32; }
    else                 { src = ffn1_w + 512*1024; dst = ffn1bt;  C = 1024; ldd = 512;  int r = bid - 1792; bx = r % 32; by = r / 32; }
    const int tx = tid & 31, ty = tid >> 5;
    const int xx = bx * 32 + tx;
#pragma unroll
    for (int j = 0; j < 4; j++)
        tile[ty + 8 * j][tx] = (bf16)src[(size_t)(by * 32 + ty + 8 * j) * C + xx];
    __syncthreads();
    const int x2 = by * 32 + tx;
#pragma unroll
    for (int j = 0; j < 4; j++)
        dst[(size_t)(bx * 32 + ty + 8 * j) * ldd + x2] = tile[tx][ty + 8 * j];
}

// ---------------- QKV GEMM (+fused RoPE epilogue) + Wcomb GEMM, ONE launch --
// BK=64 staging (R13 pattern): half the barrier drains, stride-72 LDS rows.
// blocks [0,768): QKV (M=8192,N=1536,K=512); q/k sectors apply bias+RoPE.
// blocks [768,800): Wcomb^T = ffn1bt @ out_cast^T -> fused[:,512:]
__global__ __launch_bounds__(256) void qkv_wcomb_kernel(
    const bf16* __restrict__ cat, const bf16* __restrict__ wqkv_t,
    const float* __restrict__ wqkv_b, const unsigned* __restrict__ tab,
    bf16* __restrict__ qbuf, bf16* __restrict__ kbuf, bf16* __restrict__ vbuf,
    const bf16* __restrict__ ffn1bt, const bf16* __restrict__ out_cast,
    bf16* __restrict__ fused_t)
{
    const int bid = blockIdx.x;
    const bool isqkv = bid < 768;
    const bf16* A; const bf16* Bt; int lda, m0, n0;
    if (isqkv) { A = cat;    lda = 1024; Bt = wqkv_t;   n0 = (bid % 12) * 128; m0 = (bid / 12) * 128; }
    else       { int r = bid - 768;
                 A = ffn1bt; lda = 512;  Bt = out_cast; n0 = (r & 3) * 128;    m0 = (r >> 2) * 128; }
    const int K = 512;

    const int tid = threadIdx.x;
    const int lane = tid & 63, wave = tid >> 6;
    const int wm = wave >> 1, wn = wave & 1;
    const int l15 = lane & 15, quad = lane >> 4;

    __shared__ __align__(16) char smem[36864];
    bf16* As = (bf16*)smem;            // 128x72
    bf16* Bs = (bf16*)(smem + 18432);  // 128x72
    unsigned* tabs = (unsigned*)smem;  // overlay post-loop: 128 rows x 32 pairs

    int row[4], kc[4];
    const bf16 *pA[4], *pB[4];
#pragma unroll
    for (int i = 0; i < 4; i++) {
        int c = tid + i * 256;
        row[i] = c >> 3; kc[i] = (c & 7) << 3;
        pA[i] = &A[(size_t)(m0 + row[i]) * lda + kc[i]];
        pB[i] = &Bt[(size_t)(n0 + row[i]) * K + kc[i]];
    }

    const f32x4 zero = {0.f, 0.f, 0.f, 0.f};
    f32x4 acc[4][4];
#pragma unroll
    for (int i = 0; i < 4; i++)
#pragma unroll
        for (int j = 0; j < 4; j++) acc[i][j] = zero;

    bf16x8 ra[4], rb[4];
#pragma unroll
    for (int i = 0; i < 4; i++) { ra[i] = *(const bf16x8*)pA[i]; rb[i] = *(const bf16x8*)pB[i]; }

    for (int k0 = 0; k0 < K; k0 += 64) {
        __syncthreads();
#pragma unroll
        for (int i = 0; i < 4; i++) {
            *(bf16x8*)(&As[row[i] * 72 + kc[i]]) = ra[i];
            *(bf16x8*)(&Bs[row[i] * 72 + kc[i]]) = rb[i];
        }
        __syncthreads();
        if (k0 + 64 < K) {
#pragma unroll
            for (int i = 0; i < 4; i++) {
                ra[i] = *(const bf16x8*)(pA[i] + k0 + 64);
                rb[i] = *(const bf16x8*)(pB[i] + k0 + 64);
            }
        }
#pragma unroll
        for (int kk = 0; kk < 2; kk++) {
            bf16x8 af[4], bfv[4];
#pragma unroll
            for (int t = 0; t < 4; t++) {
                af[t]  = *(const bf16x8*)(&As[(wm * 64 + t * 16 + l15) * 72 + kk * 32 + quad * 8]);
                bfv[t] = *(const bf16x8*)(&Bs[(wn * 64 + t * 16 + l15) * 72 + kk * 32 + quad * 8]);
            }
#pragma unroll
            for (int mt = 0; mt < 4; mt++)
#pragma unroll
                for (int nt = 0; nt < 4; nt++)
                    acc[mt][nt] = MFMA16(af[mt], bfv[nt], acc[mt][nt]);
        }
    }

    const int row_base = m0 + wm * 64;
    const int col_base = n0 + wn * 64;

    if (isqkv) {
        const int sector = col_base >> 9;        // 0=q 1=k 2=v, uniform per BLOCK
        const bool dorope = sector < 2;
        if (dorope) {                            // stage this block's rope table
            __syncthreads();                     // K-loop LDS reads done
#pragma unroll
            for (int ps = 0; ps < 4; ps++) {
                int idx = ps * 1024 + tid * 4;
                *(uint4*)(&tabs[idx]) = *(const uint4*)(&tab[(size_t)m0 * 32 + idx]);
            }
            __syncthreads();
        }
        const float SCQ = 0.125f * 1.44269504089f;
        bf16* dstbase = (sector == 0) ? qbuf : (sector == 1 ? kbuf : vbuf);
#pragma unroll
        for (int nt = 0; nt < 4; nt++) {
            const int col = col_base + nt * 16 + l15;
            const int cq = col & 511;
            const int h = cq >> 6, hd = cq & 63;
            const float bv = wqkv_b[col];
            const int ihalf = hd >> 1;
            const bool odd = (hd & 1) != 0;
#pragma unroll
            for (int mt = 0; mt < 4; mt++) {
#pragma unroll
                for (int r = 0; r < 4; r++) {
                    const int mrow = row_base + mt * 16 + quad * 4 + r;   // b*2048+n
                    float v = acc[mt][nt][r] + bv;
                    float o = v;
                    if (dorope) {
                        float p = __shfl_xor(v, 1);      // partner column col^1
                        const int rl = wm * 64 + mt * 16 + quad * 4 + r;  // mrow-m0
                        union { unsigned u; bf16x2 h2; } t2;
                        t2.u = tabs[rl * 32 + ihalf];
                        float cs = t2.h2[0], sn = t2.h2[1];
                        o = odd ? (p * sn + v * cs) : (v * cs - p * sn);
                        if (sector == 0) o *= SCQ;
                    }
                    const int b = mrow >> 11, n = mrow & 2047;
                    dstbase[(((size_t)b * 8 + h) * 2048 + n) * 64 + hd] = (bf16)o;
                }
            }
        }
    } else {
#pragma unroll
        for (int nt = 0; nt < 4; nt++) {
            const int col = col_base + nt * 16 + l15;
#pragma unroll
            for (int mt = 0; mt < 4; mt++) {
#pragma unroll
                for (int r = 0; r < 4; r++) {
                    const int row2 = row_base + mt * 16 + quad * 4 + r;
                    fused_t[(size_t)row2 * 1024 + 512 + col] = (bf16)acc[mt][nt][r];
                }
            }
        }
    }
}

// ---------------- 128x128 MFMA GEMM, BK=64, stride-72 LDS, for ffn1 / ffn2 --
template <int MODE>
__global__ __launch_bounds__(256) void gemm_mfma(
    const bf16* __restrict__ A, int lda, const bf16* __restrict__ Bt,
    const float* __restrict__ bias, void* __restrict__ outv,
    const float* __restrict__ auxf, int K)
{
    const int tid = threadIdx.x;
    const int lane = tid & 63, wave = tid >> 6;
    const int wm = wave >> 1, wn = wave & 1;
    const int l15 = lane & 15, quad = lane >> 4;
    const int m0 = blockIdx.y * 128;
    const int n0 = blockIdx.x * 128;

    __shared__ bf16 As[128 * 72];
    __shared__ bf16 Bs[128 * 72];

    int row[4], kc[4];
    const bf16 *pA[4], *pB[4];
#pragma unroll
    for (int i = 0; i < 4; i++) {
        int c = tid + i * 256;
        row[i] = c >> 3; kc[i] = (c & 7) << 3;
        pA[i] = &A[(size_t)(m0 + row[i]) * lda + kc[i]];
        pB[i] = &Bt[(size_t)(n0 + row[i]) * K + kc[i]];
    }

    const f32x4 zero = {0.f, 0.f, 0.f, 0.f};
    f32x4 acc[4][4];
#pragma unroll
    for (int i = 0; i < 4; i++)
#pragma unroll
        for (int j = 0; j < 4; j++) acc[i][j] = zero;

    bf16x8 ra[4], rb[4];
#pragma unroll
    for (int i = 0; i < 4; i++) { ra[i] = *(const bf16x8*)pA[i]; rb[i] = *(const bf16x8*)pB[i]; }

    for (int k0 = 0; k0 < K; k0 += 64) {
        __syncthreads();
#pragma unroll
        for (int i = 0; i < 4; i++) {
            *(bf16x8*)(&As[row[i] * 72 + kc[i]]) = ra[i];
            *(bf16x8*)(&Bs[row[i] * 72 + kc[i]]) = rb[i];
        }
        __syncthreads();
        if (k0 + 64 < K) {
#pragma unroll
            for (int i = 0; i < 4; i++) {
                ra[i] = *(const bf16x8*)(pA[i] + k0 + 64);
                rb[i] = *(const bf16x8*)(pB[i] + k0 + 64);
            }
        }
#pragma unroll
        for (int kk = 0; kk < 2; kk++) {
            bf16x8 af[4], bfv[4];
#pragma unroll
            for (int t = 0; t < 4; t++) {
                af[t]  = *(const bf16x8*)(&As[(wm * 64 + t * 16 + l15) * 72 + kk * 32 + quad * 8]);
                bfv[t] = *(const bf16x8*)(&Bs[(wn * 64 + t * 16 + l15) * 72 + kk * 32 + quad * 8]);
            }
#pragma unroll
            for (int mt = 0; mt < 4; mt++)
#pragma unroll
                for (int nt = 0; nt < 4; nt++)
                    acc[mt][nt] = MFMA16(af[mt], bfv[nt], acc[mt][nt]);
        }
    }

    const int row_base = m0 + wm * 64;
    const int col_base = n0 + wn * 64;
#pragma unroll
    for (int nt = 0; nt < 4; nt++) {
        const int col = col_base + nt * 16 + l15;
        const float bv = bias[col];
#pragma unroll
        for (int mt = 0; mt < 4; mt++) {
#pragma unroll
            for (int r = 0; r < 4; r++) {
                const int row2 = row_base + mt * 16 + quad * 4 + r;
                float v = acc[mt][nt][r] + bv;
                if constexpr (MODE == 2) {
                    ((bf16*)outv)[(size_t)row2 * 1024 + col] = (bf16)v;
                } else {
                    v += auxf[(size_t)row2 * 512 + col];
                    ((float*)outv)[(size_t)row2 * 512 + col] = v;
                }
            }
        }
    }
}

// ---------------- attention v8 (R13, best measured): PV(t-1) pipelined ------
// Grid 1024; 512 threads = 8 waves: qg(2) x kh(4 key-quarter). K+V staged
// cooperatively to LDS with one-tile register prefetch; V double-buffered so
// PV for tile t-1 (independent MFMA work) overlaps tile t's S-MFMA/exp chain.
__global__ __launch_bounds__(512) void attn_kernel(const bf16* __restrict__ qb,
                                                   const bf16* __restrict__ kb,
                                                   const bf16* __restrict__ vb,
                                                   bf16* __restrict__ cat)
{
    __shared__ __align__(16) char smem[53248];
    bf16* Ks   = (bf16*)smem;                   // [128 keys][64 dims] stride 72
    bf16* Vts0 = (bf16*)(smem + 18432);         // [64 dims][128 keys] stride 136
    bf16* Vts1 = (bf16*)(smem + 35840);

    const int tid = threadIdx.x, lane = tid & 63, wave = tid >> 6;
    const int l31 = lane & 31, half = lane >> 5;
    const int qg = wave >> 2, kh = wave & 3;
    const int bh = blockIdx.x >> 5, qt = blockIdx.x & 31;
    const int b = bh >> 3, h = bh & 7;
    const size_t base = (size_t)bh * 2048 * 64;
    const int m0 = qt * 64 + qg * 32;

    bf16x8 aq[4];
#pragma unroll
    for (int k4 = 0; k4 < 4; k4++)
        aq[k4] = *(const bf16x8*)(&qb[base + (size_t)(m0 + l31) * 64 + k4 * 16 + half * 8]);

    f32x16 accO[2];
#pragma unroll
    for (int i = 0; i < 16; i++) { accO[0][i] = 0.f; accO[1][i] = 0.f; }
    float lsum = 0.f;

    int krow[2], kcol[2];
#pragma unroll
    for (int i = 0; i < 2; i++) { int c = tid + i * 512; krow[i] = c >> 3; kcol[i] = (c & 7) << 3; }
    const int vpr = tid & 63, vdg = tid >> 6;

    bf16x8 kreg[2], vr0, vr1;
    auto prefetch = [&](int key0) {
#pragma unroll
        for (int i = 0; i < 2; i++)
            kreg[i] = *(const bf16x8*)(&kb[base + (size_t)(key0 + krow[i]) * 64 + kcol[i]]);
        vr0 = *(const bf16x8*)(&vb[base + (size_t)(key0 + 2 * vpr) * 64 + vdg * 8]);
        vr1 = *(const bf16x8*)(&vb[base + (size_t)(key0 + 2 * vpr + 1) * 64 + vdg * 8]);
    };

    const int ko = kh * 32;            // this wave's key quarter
    union Bu { bf16x8 v; unsigned u[4]; };
    Bu B0p, B1p;
    auto pv = [&](const bf16* Vr) {    // PV for the tile whose P is in B0p/B1p
#pragma unroll
        for (int dh = 0; dh < 2; dh++) {
            bf16x8 av0 = *(const bf16x8*)(&Vr[(dh * 32 + l31) * 136 + ko + half * 8]);
            bf16x8 av1 = *(const bf16x8*)(&Vr[(dh * 32 + l31) * 136 + ko + 16 + half * 8]);
            accO[dh] = MFMA32(av0, B0p.v, accO[dh]);
            accO[dh] = MFMA32(av1, B1p.v, accO[dh]);
        }
    };

    prefetch(0);
#pragma unroll
    for (int kt = 0; kt < 16; kt++) {
        bf16* Vw = (kt & 1) ? Vts1 : Vts0;
        bf16* Vr = (kt & 1) ? Vts0 : Vts1;   // previous tile's buffer
        __syncthreads();               // prior reads of Vw's buffer + Ks done
#pragma unroll
        for (int i = 0; i < 2; i++)
            *(bf16x8*)(&Ks[krow[i] * 72 + kcol[i]]) = kreg[i];
#pragma unroll
        for (int j = 0; j < 8; j++) {
            bf16x2 pr; pr[0] = vr0[j]; pr[1] = vr1[j];
            *(bf16x2*)(&Vw[(vdg * 8 + j) * 136 + 2 * vpr]) = pr;
        }
        __syncthreads();
        if (kt < 15) prefetch((kt + 1) * 128);

        // S for tile kt
        f32x16 s;
#pragma unroll
        for (int i = 0; i < 16; i++) s[i] = 0.f;
#pragma unroll
        for (int k4 = 0; k4 < 4; k4++) {
            bf16x8 ak = *(const bf16x8*)(&Ks[(ko + l31) * 72 + k4 * 16 + half * 8]);
            s = MFMA32(ak, aq[k4], s);
        }
        // PV for tile kt-1 — independent MFMA work overlapping S latency
        if (kt > 0) pv(Vr);
        // exp/pack tile kt -> B0p/B1p (consumed next iteration)
        float p[16];
#pragma unroll
        for (int r = 0; r < 16; r++) p[r] = __builtin_amdgcn_exp2f(s[r]);
        lsum += (((p[0] + p[1]) + (p[2] + p[3])) + ((p[4] + p[5]) + (p[6] + p[7])))
              + (((p[8] + p[9]) + (p[10] + p[11])) + ((p[12] + p[13]) + (p[14] + p[15])));
        unsigned pk[8];
#pragma unroll
        for (int i2 = 0; i2 < 8; i2++) {
            union { bf16x2 hh; unsigned u; } t;
            t.hh[0] = (bf16)p[2 * i2]; t.hh[1] = (bf16)p[2 * i2 + 1];
            pk[i2] = t.u;
        }
        const unsigned sa = half ? pk[0] : pk[2];
        const unsigned sb = half ? pk[1] : pk[3];
        const unsigned sc2 = half ? pk[4] : pk[6];
        const unsigned sd = half ? pk[5] : pk[7];
        const unsigned ra = (unsigned)__shfl_xor((int)sa, 32);
        const unsigned rb = (unsigned)__shfl_xor((int)sb, 32);
        const unsigned rc = (unsigned)__shfl_xor((int)sc2, 32);
        const unsigned rd = (unsigned)__shfl_xor((int)sd, 32);
        B0p.u[0] = half ? ra : pk[0];
        B0p.u[1] = half ? rb : pk[1];
        B0p.u[2] = half ? pk[2] : ra;
        B0p.u[3] = half ? pk[3] : rb;
        B1p.u[0] = half ? rc : pk[4];
        B1p.u[1] = half ? rd : pk[5];
        B1p.u[2] = half ? pk[6] : rc;
        B1p.u[3] = half ? pk[7] : rd;
    }
    // drain: PV for tile 15 (its V is in Vts1)
    pv(Vts1);

    // 4-way kh reduction per qg through LDS (stride-33 f32, conflict-free)
    auto slotp = [&](int s2) { return (float*)smem + ((s2 * 2 + qg) * 64 + lane) * 33; };
    __syncthreads();                   // all Vts/Ks reads done; overlay safe
    if (kh == 1 || kh == 3) {
        float* pr2 = slotp(kh >> 1);
#pragma unroll
        for (int dh = 0; dh < 2; dh++)
#pragma unroll
            for (int r = 0; r < 16; r++) pr2[dh * 16 + r] = accO[dh][r];
        pr2[32] = lsum;
    }
    __syncthreads();
    if (kh == 0 || kh == 2) {
        float* pr2 = slotp(kh >> 1);
#pragma unroll
        for (int dh = 0; dh < 2; dh++)
#pragma unroll
            for (int r = 0; r < 16; r++) accO[dh][r] += pr2[dh * 16 + r];
        lsum += pr2[32];
    }
    __syncthreads();
    if (kh == 2) {
        float* pr2 = slotp(0);
#pragma unroll
        for (int dh = 0; dh < 2; dh++)
#pragma unroll
            for (int r = 0; r < 16; r++) pr2[dh * 16 + r] = accO[dh][r];
        pr2[32] = lsum;
    }
    __syncthreads();
    if (kh == 0) {
        float* pr2 = slotp(0);
#pragma unroll
        for (int dh = 0; dh < 2; dh++)
#pragma unroll
            for (int r = 0; r < 16; r++) accO[dh][r] += pr2[dh * 16 + r];
        lsum += pr2[32];
        lsum += __shfl_xor(lsum, 32);  // merge key-halves
        const float inv = 1.0f / lsum;
        const int n = m0 + l31;
        bf16* aor = cat + ((size_t)b * 2048 + n) * 1024 + 512 + h * 64;
#pragma unroll
        for (int dh = 0; dh < 2; dh++) {
#pragma unroll
            for (int g = 0; g < 4; g++) {
                bf16x4 o4;
#pragma unroll
                for (int e = 0; e < 4; e++) o4[e] = (bf16)(accO[dh][g * 4 + e] * inv);
                *(bf16x4*)(&aor[dh * 32 + g * 8 + half * 4]) = o4;
            }
        }
    }
}

// ------------- LayerNorm + tanh-GELU, one block per row, in place (bf16) ---
__global__ __launch_bounds__(256) void ln_gelu_kernel(bf16* __restrict__ hb,
                                                      const float* __restrict__ g,
                                                      const float* __restrict__ bt)
{
    const int row = blockIdx.x, tid = threadIdx.x;
    const int lane = tid & 63, wave = tid >> 6;
    bf16* hr = hb + (size_t)row * 1024;
    bf16x4 hv = *(const bf16x4*)(&hr[tid * 4]);
    float v0 = hv[0], v1 = hv[1], v2 = hv[2], v3 = hv[3];
    float s = v0 + v1 + v2 + v3;
    float q = v0 * v0 + v1 * v1 + v2 * v2 + v3 * v3;
    for (int o = 32; o; o >>= 1) { s += __shfl_xor(s, o); q += __shfl_xor(q, o); }
    __shared__ float red[8];
    if (lane == 0) { red[wave] = s; red[4 + wave] = q; }
    __syncthreads();
    s = red[0] + red[1] + red[2] + red[3];
    q = red[4] + red[5] + red[6] + red[7];
    const float mu = s * (1.f / 1024.f);
    const float rstd = rsqrtf(q * (1.f / 1024.f) - mu * mu + 1e-5f);
    const float4 gv = *(const float4*)(&g[tid * 4]);
    const float4 bv = *(const float4*)(&bt[tid * 4]);
    float vv[4] = {v0, v1, v2, v3};
    const float gg[4] = {gv.x, gv.y, gv.z, gv.w};
    const float bb[4] = {bv.x, bv.y, bv.z, bv.w};
    bf16x4 o4;
#pragma unroll
    for (int i = 0; i < 4; i++) {
        float y = (vv[i] - mu) * rstd * gg[i] + bb[i];
        float t = 1.5957691216f * y * (1.0f + 0.044715f * y * y);
        float e = __builtin_amdgcn_exp2f(-1.44269504089f * t);
        o4[i] = (bf16)(y * __builtin_amdgcn_rcpf(1.0f + e));
    }
    *(bf16x4*)(&hr[tid * 4]) = o4;
}

// ---------------------------------------------------------------------------
extern "C" void kernel_launch(void* const* d_in, const int* in_sizes, int n_in,
                              void* d_out, int out_size, void* d_ws, size_t ws_size,
                              hipStream_t stream) {
    (void)in_sizes; (void)n_in; (void)out_size; (void)ws_size;
    const float* x      = (const float*)d_in[0];
    const float* freqs  = (const float*)d_in[1];
    const float* wqkv_w = (const float*)d_in[2];
    const float* wqkv_b = (const float*)d_in[3];
    const float* out_w  = (const float*)d_in[4];
    const float* out_b  = (const float*)d_in[5];
    const float* ffn1_w = (const float*)d_in[6];
    const float* ffn1_b = (const float*)d_in[7];
    const float* ln_g   = (const float*)d_in[8];
    const float* ln_b   = (const float*)d_in[9];
    const float* ffn2_w = (const float*)d_in[10];
    const float* ffn2_b = (const float*)d_in[11];
    float* out = (float*)d_out;
    bf16* ws   = (bf16*)d_ws;

    bf16* wqkv_t   = ws;                              // 1536x512
    bf16* ffn2_t   = wqkv_t + 1536 * 512;             // 512x1024
    bf16* fused_t  = ffn2_t + 512 * 1024;             // 1024x1024 [Wtop^T | Wcomb^T]
    bf16* ffn1bt   = fused_t + 1024 * 1024;           // 1024x512 (Wbot^T)
    bf16* out_cast = ffn1bt + 1024 * 512;             // 512x512
    bf16* cat      = out_cast + 512 * 512;            // 8192x1024
    bf16* qbuf     = cat + (size_t)8192 * 1024;       // (B,H,N,64)
    bf16* kbuf     = qbuf + (size_t)8192 * 512;
    bf16* vbuf     = kbuf + (size_t)8192 * 512;
    float* bias_f  = (float*)(vbuf + (size_t)8192 * 512);   // 1024 f32
    unsigned* tab  = (unsigned*)(bias_f + 1024);      // 4x2048x32 packed bf16 (cos,sin)
    bf16* hbuf     = qbuf;                            // overlays q+k (dead post-attn)

    prep_kernel<<<6928, 256, 0, stream>>>(wqkv_w, out_w, ffn1_w, ffn2_w, x, freqs,
                                          ffn1_b, out_b,
                                          wqkv_t, ffn2_t, fused_t, ffn1bt, out_cast, cat,
                                          bias_f, tab);
    qkv_wcomb_kernel<<<800, 256, 0, stream>>>(cat, wqkv_t, wqkv_b, tab, qbuf, kbuf, vbuf,
                                              ffn1bt, out_cast, fused_t);
    attn_kernel<<<1024, 512, 0, stream>>>(qbuf, kbuf, vbuf, cat);
    gemm_mfma<2><<<dim3(8, 64), 256, 0, stream>>>(cat, 1024, fused_t, bias_f, hbuf, nullptr, 1024);
    ln_gelu_kernel<<<8192, 256, 0, stream>>>(hbuf, ln_g, ln_b);
    gemm_mfma<3><<<dim3(4, 64), 256, 0, stream>>>(hbuf, 1024, ffn2_t, ffn2_b, out, x, 1024);
}

// Round 16
// 244.811 us; speedup vs baseline: 1.2822x; 1.0006x over previous
//
#include <hip/hip_runtime.h>
#include <hip/hip_bf16.h>
#include <math.h>

// B=4, N=2048, D=512, H=8, HD=64. Inputs/outputs FP32; internals bf16-MFMA.
// Fusions: (1) h = cat@[Wtop;Wcomb], Wcomb = out_w@Wbot precomputed -> no proj GEMM;
// (2) RoPE folded into QKV epilogue via precomputed bf16 (cos,sin) table.
// R10+R14 law: hot MFMA operands stage cooperatively through LDS w/ prefetch.
// R8: no blind __launch_bounds__ 2nd arg. R13/R15: BK=64 stride-72 staging.
// R16: ffn GEMMs use 32x32x16 MFMA (15% better rate, half the instructions);
//      ln_gelu one-wave-per-row (barrier-free).
typedef __bf16 bf16;
typedef __bf16 bf16x2 __attribute__((ext_vector_type(2)));
typedef __bf16 bf16x4 __attribute__((ext_vector_type(4)));
typedef __bf16 bf16x8 __attribute__((ext_vector_type(8)));
typedef float f32x4 __attribute__((ext_vector_type(4)));
typedef float f32x16 __attribute__((ext_vector_type(16)));

#define MFMA16(a, b, c) __builtin_amdgcn_mfma_f32_16x16x32_bf16(a, b, c, 0, 0, 0)
#define MFMA32(a, b, c) __builtin_amdgcn_mfma_f32_32x32x16_bf16(a, b, c, 0, 0, 0)

// MFMA fragment facts (guide-verified on gfx950):
//  16x16x32: A: lane holds A[m=lane&15][k=(lane>>4)*8+j]; C/D: reg r -> D[(lane>>4)*4+r][lane&15]
//  32x32x16: A: lane holds A[m=lane&31][k=(lane>>5)*8+j]; B: B[k=(lane>>5)*8+j][n=lane&31]
//            C/D: reg r -> D[row=(r&3)+8*(r>>2)+4*(lane>>5)][col=lane&31]

// ------------- prep: transposes/casts + x-cast + bias-fuse + rope table -----
__global__ __launch_bounds__(256) void prep_kernel(
    const float* __restrict__ wqkv_w, const float* __restrict__ out_w,
    const float* __restrict__ ffn1_w, const float* __restrict__ ffn2_w,
    const float* __restrict__ x, const float* __restrict__ freqs,
    const float* __restrict__ ffn1_b, const float* __restrict__ out_b,
    bf16* __restrict__ wqkv_t, bf16* __restrict__ ffn2_t,
    bf16* __restrict__ fused_t, bf16* __restrict__ ffn1bt,
    bf16* __restrict__ out_cast, bf16* __restrict__ cat,
    float* __restrict__ bias_f, unsigned* __restrict__ tab)
{
    const int bid = blockIdx.x, tid = threadIdx.x;
    __shared__ bf16 tile[32][33];
    __shared__ float red[256];
    if (bid >= 6672) {                 // rope table: 256 blocks, packed bf16 (cos,sin)
        int i = (bid - 6672) * 1024 + tid * 4;
        const float4 f = *(const float4*)(&freqs[i]);
        float s0, c0, s1, c1, s2, c2, s3, c3;
        __sincosf(f.x, &s0, &c0); __sincosf(f.y, &s1, &c1);
        __sincosf(f.z, &s2, &c2); __sincosf(f.w, &s3, &c3);
        union { bf16x2 h2; unsigned u; } p0, p1, p2, p3;
        p0.h2[0] = (bf16)c0; p0.h2[1] = (bf16)s0;
        p1.h2[0] = (bf16)c1; p1.h2[1] = (bf16)s1;
        p2.h2[0] = (bf16)c2; p2.h2[1] = (bf16)s2;
        p3.h2[0] = (bf16)c3; p3.h2[1] = (bf16)s3;
        uint4 o = {p0.u, p1.u, p2.u, p3.u};
        *(uint4*)(&tab[i]) = o;
        return;
    }
    if (bid >= 6656) {                 // bias_f[n] = ffn1_b[n] + sum_i out_b[i]*Wbot[i][n]
        const int n = (bid - 6656) * 64 + (tid & 63);
        const int ic = tid >> 6;
        float acc = 0.f;
#pragma unroll 8
        for (int i = ic * 128; i < ic * 128 + 128; i++)
            acc += out_b[i] * ffn1_w[(size_t)(512 + i) * 1024 + n];
        red[tid] = acc;
        __syncthreads();
        if (tid < 64)
            bias_f[n] = ffn1_b[n] + red[tid] + red[tid + 64] + red[tid + 128] + red[tid + 192];
        return;
    }
    if (bid >= 2560) {                 // cast_x: 4096 blocks
        int i = (bid - 2560) * 256 + tid;
        int row = i >> 7, col = (i & 127) << 2;
        const float4 v = *(const float4*)(&x[(size_t)row * 512 + col]);
        bf16x4 o; o[0] = (bf16)v.x; o[1] = (bf16)v.y; o[2] = (bf16)v.z; o[3] = (bf16)v.w;
        *(bf16x4*)(&cat[(size_t)row * 1024 + col]) = o;
        return;
    }
    if (bid >= 2304) {                 // out_w cast: 256 blocks (512x512)
        int i = (bid - 2304) * 1024 + tid * 4;
        const float4 v = *(const float4*)(&out_w[i]);
        bf16x4 o; o[0] = (bf16)v.x; o[1] = (bf16)v.y; o[2] = (bf16)v.z; o[3] = (bf16)v.w;
        *(bf16x4*)(&out_cast[i]) = o;
        return;
    }
    // transposes: src (RxC) f32 -> dst (CxR region) bf16 with dst stride ldd
    const float* src; bf16* dst; int C, ldd, bx, by;
    if (bid < 768)       { src = wqkv_w;            dst = wqkv_t;  C = 1536; ldd = 512;  int r = bid;        bx = r % 48; by = r / 48; }
    else if (bid < 1280) { src = ffn2_w;            dst = ffn2_t;  C = 512;  ldd = 1024; int r = bid - 768;  bx = r % 16; by = r / 16; }
    else if (bid < 1792) { src = ffn1_w;            dst = fused_t; C = 1024; ldd = 1024; int r = bid - 1280; bx = r % 32; by = r / 32; }
    else                 { src = ffn1_w + 512*1024; dst = ffn1bt;  C = 1024; ldd = 512;  int r = bid - 1792; bx = r % 32; by = r / 32; }
    const int tx = tid & 31, ty = tid >> 5;
    const int xx = bx * 32 + tx;
#pragma unroll
    for (int j = 0; j < 4; j++)
        tile[ty + 8 * j][tx] = (bf16)src[(size_t)(by * 32 + ty + 8 * j) * C + xx];
    __syncthreads();
    const int x2 = by * 32 + tx;
#pragma unroll
    for (int j = 0; j < 4; j++)
        dst[(size_t)(bx * 32 + ty + 8 * j) * ldd + x2] = tile[tx][ty + 8 * j];
}

// ---------------- QKV GEMM (+fused RoPE epilogue) + Wcomb GEMM, ONE launch --
// BK=64 staging (R13 pattern): half the barrier drains, stride-72 LDS rows.
__global__ __launch_bounds__(256) void qkv_wcomb_kernel(
    const bf16* __restrict__ cat, const bf16* __restrict__ wqkv_t,
    const float* __restrict__ wqkv_b, const unsigned* __restrict__ tab,
    bf16* __restrict__ qbuf, bf16* __restrict__ kbuf, bf16* __restrict__ vbuf,
    const bf16* __restrict__ ffn1bt, const bf16* __restrict__ out_cast,
    bf16* __restrict__ fused_t)
{
    const int bid = blockIdx.x;
    const bool isqkv = bid < 768;
    const bf16* A; const bf16* Bt; int lda, m0, n0;
    if (isqkv) { A = cat;    lda = 1024; Bt = wqkv_t;   n0 = (bid % 12) * 128; m0 = (bid / 12) * 128; }
    else       { int r = bid - 768;
                 A = ffn1bt; lda = 512;  Bt = out_cast; n0 = (r & 3) * 128;    m0 = (r >> 2) * 128; }
    const int K = 512;

    const int tid = threadIdx.x;
    const int lane = tid & 63, wave = tid >> 6;
    const int wm = wave >> 1, wn = wave & 1;
    const int l15 = lane & 15, quad = lane >> 4;

    __shared__ __align__(16) char smem[36864];
    bf16* As = (bf16*)smem;            // 128x72
    bf16* Bs = (bf16*)(smem + 18432);  // 128x72
    unsigned* tabs = (unsigned*)smem;  // overlay post-loop: 128 rows x 32 pairs

    int row[4], kc[4];
    const bf16 *pA[4], *pB[4];
#pragma unroll
    for (int i = 0; i < 4; i++) {
        int c = tid + i * 256;
        row[i] = c >> 3; kc[i] = (c & 7) << 3;
        pA[i] = &A[(size_t)(m0 + row[i]) * lda + kc[i]];
        pB[i] = &Bt[(size_t)(n0 + row[i]) * K + kc[i]];
    }

    const f32x4 zero = {0.f, 0.f, 0.f, 0.f};
    f32x4 acc[4][4];
#pragma unroll
    for (int i = 0; i < 4; i++)
#pragma unroll
        for (int j = 0; j < 4; j++) acc[i][j] = zero;

    bf16x8 ra[4], rb[4];
#pragma unroll
    for (int i = 0; i < 4; i++) { ra[i] = *(const bf16x8*)pA[i]; rb[i] = *(const bf16x8*)pB[i]; }

    for (int k0 = 0; k0 < K; k0 += 64) {
        __syncthreads();
#pragma unroll
        for (int i = 0; i < 4; i++) {
            *(bf16x8*)(&As[row[i] * 72 + kc[i]]) = ra[i];
            *(bf16x8*)(&Bs[row[i] * 72 + kc[i]]) = rb[i];
        }
        __syncthreads();
        if (k0 + 64 < K) {
#pragma unroll
            for (int i = 0; i < 4; i++) {
                ra[i] = *(const bf16x8*)(pA[i] + k0 + 64);
                rb[i] = *(const bf16x8*)(pB[i] + k0 + 64);
            }
        }
#pragma unroll
        for (int kk = 0; kk < 2; kk++) {
            bf16x8 af[4], bfv[4];
#pragma unroll
            for (int t = 0; t < 4; t++) {
                af[t]  = *(const bf16x8*)(&As[(wm * 64 + t * 16 + l15) * 72 + kk * 32 + quad * 8]);
                bfv[t] = *(const bf16x8*)(&Bs[(wn * 64 + t * 16 + l15) * 72 + kk * 32 + quad * 8]);
            }
#pragma unroll
            for (int mt = 0; mt < 4; mt++)
#pragma unroll
                for (int nt = 0; nt < 4; nt++)
                    acc[mt][nt] = MFMA16(af[mt], bfv[nt], acc[mt][nt]);
        }
    }

    const int row_base = m0 + wm * 64;
    const int col_base = n0 + wn * 64;

    if (isqkv) {
        const int sector = col_base >> 9;        // 0=q 1=k 2=v, uniform per BLOCK
        const bool dorope = sector < 2;
        if (dorope) {                            // stage this block's rope table
            __syncthreads();                     // K-loop LDS reads done
#pragma unroll
            for (int ps = 0; ps < 4; ps++) {
                int idx = ps * 1024 + tid * 4;
                *(uint4*)(&tabs[idx]) = *(const uint4*)(&tab[(size_t)m0 * 32 + idx]);
            }
            __syncthreads();
        }
        const float SCQ = 0.125f * 1.44269504089f;
        bf16* dstbase = (sector == 0) ? qbuf : (sector == 1 ? kbuf : vbuf);
#pragma unroll
        for (int nt = 0; nt < 4; nt++) {
            const int col = col_base + nt * 16 + l15;
            const int cq = col & 511;
            const int h = cq >> 6, hd = cq & 63;
            const float bv = wqkv_b[col];
            const int ihalf = hd >> 1;
            const bool odd = (hd & 1) != 0;
#pragma unroll
            for (int mt = 0; mt < 4; mt++) {
#pragma unroll
                for (int r = 0; r < 4; r++) {
                    const int mrow = row_base + mt * 16 + quad * 4 + r;   // b*2048+n
                    float v = acc[mt][nt][r] + bv;
                    float o = v;
                    if (dorope) {
                        float p = __shfl_xor(v, 1);      // partner column col^1
                        const int rl = wm * 64 + mt * 16 + quad * 4 + r;  // mrow-m0
                        union { unsigned u; bf16x2 h2; } t2;
                        t2.u = tabs[rl * 32 + ihalf];
                        float cs = t2.h2[0], sn = t2.h2[1];
                        o = odd ? (p * sn + v * cs) : (v * cs - p * sn);
                        if (sector == 0) o *= SCQ;
                    }
                    const int b = mrow >> 11, n = mrow & 2047;
                    dstbase[(((size_t)b * 8 + h) * 2048 + n) * 64 + hd] = (bf16)o;
                }
            }
        }
    } else {
#pragma unroll
        for (int nt = 0; nt < 4; nt++) {
            const int col = col_base + nt * 16 + l15;
#pragma unroll
            for (int mt = 0; mt < 4; mt++) {
#pragma unroll
                for (int r = 0; r < 4; r++) {
                    const int row2 = row_base + mt * 16 + quad * 4 + r;
                    fused_t[(size_t)row2 * 1024 + 512 + col] = (bf16)acc[mt][nt][r];
                }
            }
        }
    }
}

// ---------------- 128x128 GEMM, 32x32x16 MFMA, BK=64, stride-72 LDS ---------
// Wave covers 64x64 as 2x2 tiles of 32x32. Per BK=64: 16 ds_read_b128 +
// 16 MFMA32 (vs 32 MFMA16) — same staging, better matrix-pipe rate.
// MODE 2: ffn1-fused -> bias, store h (bf16). MODE 3: ffn2 -> bias + x, f32.
template <int MODE>
__global__ __launch_bounds__(256) void gemm_mfma(
    const bf16* __restrict__ A, int lda, const bf16* __restrict__ Bt,
    const float* __restrict__ bias, void* __restrict__ outv,
    const float* __restrict__ auxf, int K)
{
    const int tid = threadIdx.x;
    const int lane = tid & 63, wave = tid >> 6;
    const int wm = wave >> 1, wn = wave & 1;
    const int l31 = lane & 31, half = lane >> 5;
    const int m0 = blockIdx.y * 128;
    const int n0 = blockIdx.x * 128;

    __shared__ bf16 As[128 * 72];
    __shared__ bf16 Bs[128 * 72];

    int row[4], kc[4];
    const bf16 *pA[4], *pB[4];
#pragma unroll
    for (int i = 0; i < 4; i++) {
        int c = tid + i * 256;
        row[i] = c >> 3; kc[i] = (c & 7) << 3;
        pA[i] = &A[(size_t)(m0 + row[i]) * lda + kc[i]];
        pB[i] = &Bt[(size_t)(n0 + row[i]) * K + kc[i]];
    }

    f32x16 acc[2][2];
#pragma unroll
    for (int i = 0; i < 2; i++)
#pragma unroll
        for (int j = 0; j < 2; j++)
#pragma unroll
            for (int e = 0; e < 16; e++) acc[i][j][e] = 0.f;

    bf16x8 ra[4], rb[4];
#pragma unroll
    for (int i = 0; i < 4; i++) { ra[i] = *(const bf16x8*)pA[i]; rb[i] = *(const bf16x8*)pB[i]; }

    for (int k0 = 0; k0 < K; k0 += 64) {
        __syncthreads();
#pragma unroll
        for (int i = 0; i < 4; i++) {
            *(bf16x8*)(&As[row[i] * 72 + kc[i]]) = ra[i];
            *(bf16x8*)(&Bs[row[i] * 72 + kc[i]]) = rb[i];
        }
        __syncthreads();
        if (k0 + 64 < K) {
#pragma unroll
            for (int i = 0; i < 4; i++) {
                ra[i] = *(const bf16x8*)(pA[i] + k0 + 64);
                rb[i] = *(const bf16x8*)(pB[i] + k0 + 64);
            }
        }
        // 4 k-steps of 16; A-frag: lane m = rt*32+l31, k = half*8+j
#pragma unroll
        for (int kk = 0; kk < 4; kk++) {
            bf16x8 af[2], bfv[2];
#pragma unroll
            for (int t = 0; t < 2; t++) {
                af[t]  = *(const bf16x8*)(&As[(wm * 64 + t * 32 + l31) * 72 + kk * 16 + half * 8]);
                bfv[t] = *(const bf16x8*)(&Bs[(wn * 64 + t * 32 + l31) * 72 + kk * 16 + half * 8]);
            }
#pragma unroll
            for (int mt = 0; mt < 2; mt++)
#pragma unroll
                for (int nt = 0; nt < 2; nt++)
                    acc[mt][nt] = MFMA32(af[mt], bfv[nt], acc[mt][nt]);
        }
    }

    const int row_base = m0 + wm * 64;
    const int col_base = n0 + wn * 64;
#pragma unroll
    for (int nt = 0; nt < 2; nt++) {
        const int col = col_base + nt * 32 + l31;
        const float bv = bias[col];
#pragma unroll
        for (int mt = 0; mt < 2; mt++) {
#pragma unroll
            for (int r = 0; r < 16; r++) {
                const int row2 = row_base + mt * 32 + (r & 3) + 8 * (r >> 2) + 4 * half;
                float v = acc[mt][nt][r] + bv;
                if constexpr (MODE == 2) {
                    ((bf16*)outv)[(size_t)row2 * 1024 + col] = (bf16)v;
                } else {
                    v += auxf[(size_t)row2 * 512 + col];
                    ((float*)outv)[(size_t)row2 * 512 + col] = v;
                }
            }
        }
    }
}

// ---------------- attention v8 (R13, best measured): PV(t-1) pipelined ------
__global__ __launch_bounds__(512) void attn_kernel(const bf16* __restrict__ qb,
                                                   const bf16* __restrict__ kb,
                                                   const bf16* __restrict__ vb,
                                                   bf16* __restrict__ cat)
{
    __shared__ __align__(16) char smem[53248];
    bf16* Ks   = (bf16*)smem;                   // [128 keys][64 dims] stride 72
    bf16* Vts0 = (bf16*)(smem + 18432);         // [64 dims][128 keys] stride 136
    bf16* Vts1 = (bf16*)(smem + 35840);

    const int tid = threadIdx.x, lane = tid & 63, wave = tid >> 6;
    const int l31 = lane & 31, half = lane >> 5;
    const int qg = wave >> 2, kh = wave & 3;
    const int bh = blockIdx.x >> 5, qt = blockIdx.x & 31;
    const int b = bh >> 3, h = bh & 7;
    const size_t base = (size_t)bh * 2048 * 64;
    const int m0 = qt * 64 + qg * 32;

    bf16x8 aq[4];
#pragma unroll
    for (int k4 = 0; k4 < 4; k4++)
        aq[k4] = *(const bf16x8*)(&qb[base + (size_t)(m0 + l31) * 64 + k4 * 16 + half * 8]);

    f32x16 accO[2];
#pragma unroll
    for (int i = 0; i < 16; i++) { accO[0][i] = 0.f; accO[1][i] = 0.f; }
    float lsum = 0.f;

    int krow[2], kcol[2];
#pragma unroll
    for (int i = 0; i < 2; i++) { int c = tid + i * 512; krow[i] = c >> 3; kcol[i] = (c & 7) << 3; }
    const int vpr = tid & 63, vdg = tid >> 6;

    bf16x8 kreg[2], vr0, vr1;
    auto prefetch = [&](int key0) {
#pragma unroll
        for (int i = 0; i < 2; i++)
            kreg[i] = *(const bf16x8*)(&kb[base + (size_t)(key0 + krow[i]) * 64 + kcol[i]]);
        vr0 = *(const bf16x8*)(&vb[base + (size_t)(key0 + 2 * vpr) * 64 + vdg * 8]);
        vr1 = *(const bf16x8*)(&vb[base + (size_t)(key0 + 2 * vpr + 1) * 64 + vdg * 8]);
    };

    const int ko = kh * 32;            // this wave's key quarter
    union Bu { bf16x8 v; unsigned u[4]; };
    Bu B0p, B1p;
    auto pv = [&](const bf16* Vr) {    // PV for the tile whose P is in B0p/B1p
#pragma unroll
        for (int dh = 0; dh < 2; dh++) {
            bf16x8 av0 = *(const bf16x8*)(&Vr[(dh * 32 + l31) * 136 + ko + half * 8]);
            bf16x8 av1 = *(const bf16x8*)(&Vr[(dh * 32 + l31) * 136 + ko + 16 + half * 8]);
            accO[dh] = MFMA32(av0, B0p.v, accO[dh]);
            accO[dh] = MFMA32(av1, B1p.v, accO[dh]);
        }
    };

    prefetch(0);
#pragma unroll
    for (int kt = 0; kt < 16; kt++) {
        bf16* Vw = (kt & 1) ? Vts1 : Vts0;
        bf16* Vr = (kt & 1) ? Vts0 : Vts1;   // previous tile's buffer
        __syncthreads();               // prior reads of Vw's buffer + Ks done
#pragma unroll
        for (int i = 0; i < 2; i++)
            *(bf16x8*)(&Ks[krow[i] * 72 + kcol[i]]) = kreg[i];
#pragma unroll
        for (int j = 0; j < 8; j++) {
            bf16x2 pr; pr[0] = vr0[j]; pr[1] = vr1[j];
            *(bf16x2*)(&Vw[(vdg * 8 + j) * 136 + 2 * vpr]) = pr;
        }
        __syncthreads();
        if (kt < 15) prefetch((kt + 1) * 128);

        // S for tile kt
        f32x16 s;
#pragma unroll
        for (int i = 0; i < 16; i++) s[i] = 0.f;
#pragma unroll
        for (int k4 = 0; k4 < 4; k4++) {
            bf16x8 ak = *(const bf16x8*)(&Ks[(ko + l31) * 72 + k4 * 16 + half * 8]);
            s = MFMA32(ak, aq[k4], s);
        }
        // PV for tile kt-1 — independent MFMA work overlapping S latency
        if (kt > 0) pv(Vr);
        // exp/pack tile kt -> B0p/B1p (consumed next iteration)
        float p[16];
#pragma unroll
        for (int r = 0; r < 16; r++) p[r] = __builtin_amdgcn_exp2f(s[r]);
        lsum += (((p[0] + p[1]) + (p[2] + p[3])) + ((p[4] + p[5]) + (p[6] + p[7])))
              + (((p[8] + p[9]) + (p[10] + p[11])) + ((p[12] + p[13]) + (p[14] + p[15])));
        unsigned pk[8];
#pragma unroll
        for (int i2 = 0; i2 < 8; i2++) {
            union { bf16x2 hh; unsigned u; } t;
            t.hh[0] = (bf16)p[2 * i2]; t.hh[1] = (bf16)p[2 * i2 + 1];
            pk[i2] = t.u;
        }
        const unsigned sa = half ? pk[0] : pk[2];
        const unsigned sb = half ? pk[1] : pk[3];
        const unsigned sc2 = half ? pk[4] : pk[6];
        const unsigned sd = half ? pk[5] : pk[7];
        const unsigned ra = (unsigned)__shfl_xor((int)sa, 32);
        const unsigned rb = (unsigned)__shfl_xor((int)sb, 32);
        const unsigned rc = (unsigned)__shfl_xor((int)sc2, 32);
        const unsigned rd = (unsigned)__shfl_xor((int)sd, 32);
        B0p.u[0] = half ? ra : pk[0];
        B0p.u[1] = half ? rb : pk[1];
        B0p.u[2] = half ? pk[2] : ra;
        B0p.u[3] = half ? pk[3] : rb;
        B1p.u[0] = half ? rc : pk[4];
        B1p.u[1] = half ? rd : pk[5];
        B1p.u[2] = half ? pk[6] : rc;
        B1p.u[3] = half ? pk[7] : rd;
    }
    // drain: PV for tile 15 (its V is in Vts1)
    pv(Vts1);

    // 4-way kh reduction per qg through LDS (stride-33 f32, conflict-free)
    auto slotp = [&](int s2) { return (float*)smem + ((s2 * 2 + qg) * 64 + lane) * 33; };
    __syncthreads();                   // all Vts/Ks reads done; overlay safe
    if (kh == 1 || kh == 3) {
        float* pr2 = slotp(kh >> 1);
#pragma unroll
        for (int dh = 0; dh < 2; dh++)
#pragma unroll
            for (int r = 0; r < 16; r++) pr2[dh * 16 + r] = accO[dh][r];
        pr2[32] = lsum;
    }
    __syncthreads();
    if (kh == 0 || kh == 2) {
        float* pr2 = slotp(kh >> 1);
#pragma unroll
        for (int dh = 0; dh < 2; dh++)
#pragma unroll
            for (int r = 0; r < 16; r++) accO[dh][r] += pr2[dh * 16 + r];
        lsum += pr2[32];
    }
    __syncthreads();
    if (kh == 2) {
        float* pr2 = slotp(0);
#pragma unroll
        for (int dh = 0; dh < 2; dh++)
#pragma unroll
            for (int r = 0; r < 16; r++) pr2[dh * 16 + r] = accO[dh][r];
        pr2[32] = lsum;
    }
    __syncthreads();
    if (kh == 0) {
        float* pr2 = slotp(0);
#pragma unroll
        for (int dh = 0; dh < 2; dh++)
#pragma unroll
            for (int r = 0; r < 16; r++) accO[dh][r] += pr2[dh * 16 + r];
        lsum += pr2[32];
        lsum += __shfl_xor(lsum, 32);  // merge key-halves
        const float inv = 1.0f / lsum;
        const int n = m0 + l31;
        bf16* aor = cat + ((size_t)b * 2048 + n) * 1024 + 512 + h * 64;
#pragma unroll
        for (int dh = 0; dh < 2; dh++) {
#pragma unroll
            for (int g = 0; g < 4; g++) {
                bf16x4 o4;
#pragma unroll
                for (int e = 0; e < 4; e++) o4[e] = (bf16)(accO[dh][g * 4 + e] * inv);
                *(bf16x4*)(&aor[dh * 32 + g * 8 + half * 4]) = o4;
            }
        }
    }
}

// ------------- LayerNorm + tanh-GELU: ONE WAVE PER ROW, barrier-free --------
// 4 rows/block (wave = row); lane holds 16 elems (2x bf16x8); 64-lane
// butterfly reduction; no LDS, no __syncthreads.
__global__ __launch_bounds__(256) void ln_gelu_kernel(bf16* __restrict__ hb,
                                                      const float* __restrict__ g,
                                                      const float* __restrict__ bt)
{
    const int lane = threadIdx.x & 63, wave = threadIdx.x >> 6;
    const int row = blockIdx.x * 4 + wave;
    bf16* hr = hb + (size_t)row * 1024;
    bf16x8 h0 = *(const bf16x8*)(&hr[lane * 8]);
    bf16x8 h1 = *(const bf16x8*)(&hr[512 + lane * 8]);
    float v[16];
#pragma unroll
    for (int i = 0; i < 8; i++) { v[i] = h0[i]; v[8 + i] = h1[i]; }
    float s = 0.f, q = 0.f;
#pragma unroll
    for (int i = 0; i < 16; i++) { s += v[i]; q += v[i] * v[i]; }
    for (int o = 32; o; o >>= 1) { s += __shfl_xor(s, o); q += __shfl_xor(q, o); }
    const float mu = s * (1.f / 1024.f);
    const float rstd = rsqrtf(q * (1.f / 1024.f) - mu * mu + 1e-5f);
    float gg[16], bb[16];
#pragma unroll
    for (int c = 0; c < 2; c++) {
#pragma unroll
        for (int p = 0; p < 2; p++) {
            const float4 gv = *(const float4*)(&g[c * 512 + lane * 8 + p * 4]);
            const float4 bv = *(const float4*)(&bt[c * 512 + lane * 8 + p * 4]);
            gg[c * 8 + p * 4 + 0] = gv.x; gg[c * 8 + p * 4 + 1] = gv.y;
            gg[c * 8 + p * 4 + 2] = gv.z; gg[c * 8 + p * 4 + 3] = gv.w;
            bb[c * 8 + p * 4 + 0] = bv.x; bb[c * 8 + p * 4 + 1] = bv.y;
            bb[c * 8 + p * 4 + 2] = bv.z; bb[c * 8 + p * 4 + 3] = bv.w;
        }
    }
    bf16x8 o0, o1;
#pragma unroll
    for (int i = 0; i < 16; i++) {
        float y = (v[i] - mu) * rstd * gg[i] + bb[i];
        float t = 1.5957691216f * y * (1.0f + 0.044715f * y * y);
        float e = __builtin_amdgcn_exp2f(-1.44269504089f * t);
        float ge = y * __builtin_amdgcn_rcpf(1.0f + e);
        if (i < 8) o0[i] = (bf16)ge; else o1[i - 8] = (bf16)ge;
    }
    *(bf16x8*)(&hr[lane * 8]) = o0;
    *(bf16x8*)(&hr[512 + lane * 8]) = o1;
}

// ---------------------------------------------------------------------------
extern "C" void kernel_launch(void* const* d_in, const int* in_sizes, int n_in,
                              void* d_out, int out_size, void* d_ws, size_t ws_size,
                              hipStream_t stream) {
    (void)in_sizes; (void)n_in; (void)out_size; (void)ws_size;
    const float* x      = (const float*)d_in[0];
    const float* freqs  = (const float*)d_in[1];
    const float* wqkv_w = (const float*)d_in[2];
    const float* wqkv_b = (const float*)d_in[3];
    const float* out_w  = (const float*)d_in[4];
    const float* out_b  = (const float*)d_in[5];
    const float* ffn1_w = (const float*)d_in[6];
    const float* ffn1_b = (const float*)d_in[7];
    const float* ln_g   = (const float*)d_in[8];
    const float* ln_b   = (const float*)d_in[9];
    const float* ffn2_w = (const float*)d_in[10];
    const float* ffn2_b = (const float*)d_in[11];
    float* out = (float*)d_out;
    bf16* ws   = (bf16*)d_ws;

    bf16* wqkv_t   = ws;                              // 1536x512
    bf16* ffn2_t   = wqkv_t + 1536 * 512;             // 512x1024
    bf16* fused_t  = ffn2_t + 512 * 1024;             // 1024x1024 [Wtop^T | Wcomb^T]
    bf16* ffn1bt   = fused_t + 1024 * 1024;           // 1024x512 (Wbot^T)
    bf16* out_cast = ffn1bt + 1024 * 512;             // 512x512
    bf16* cat      = out_cast + 512 * 512;            // 8192x1024
    bf16* qbuf     = cat + (size_t)8192 * 1024;       // (B,H,N,64)
    bf16* kbuf     = qbuf + (size_t)8192 * 512;
    bf16* vbuf     = kbuf + (size_t)8192 * 512;
    float* bias_f  = (float*)(vbuf + (size_t)8192 * 512);   // 1024 f32
    unsigned* tab  = (unsigned*)(bias_f + 1024);      // 4x2048x32 packed bf16 (cos,sin)
    bf16* hbuf     = qbuf;                            // overlays q+k (dead post-attn)

    prep_kernel<<<6928, 256, 0, stream>>>(wqkv_w, out_w, ffn1_w, ffn2_w, x, freqs,
                                          ffn1_b, out_b,
                                          wqkv_t, ffn2_t, fused_t, ffn1bt, out_cast, cat,
                                          bias_f, tab);
    qkv_wcomb_kernel<<<800, 256, 0, stream>>>(cat, wqkv_t, wqkv_b, tab, qbuf, kbuf, vbuf,
                                              ffn1bt, out_cast, fused_t);
    attn_kernel<<<1024, 512, 0, stream>>>(qbuf, kbuf, vbuf, cat);
    gemm_mfma<2><<<dim3(8, 64), 256, 0, stream>>>(cat, 1024, fused_t, bias_f, hbuf, nullptr, 1024);
    ln_gelu_kernel<<<2048, 256, 0, stream>>>(hbuf, ln_g, ln_b);
    gemm_mfma<3><<<dim3(4, 64), 256, 0, stream>>>(hbuf, 1024, ffn2_t, ffn2_b, out, x, 1024);
}